// Round 3
// baseline (200.059 us; speedup 1.0000x reference)
//
#include <hip/hip_runtime.h>

// Segment-mean pooling: feats [N, 256] fp32, segment_ids [N] sorted int32,
// out [S, 256] fp32, S = out_size / 256.
//
// One WAVE per segment (256 cols = 64 float4 = 64 lanes -> one column per
// lane). 256-thread block = 4 waves = 4 consecutive segments. No LDS, no
// __syncthreads: each wave binary-searches its own bounds (all lanes search,
// lane parity picks target s vs s+1, broadcast via shuffle), streams its rows
// with a 4-deep unrolled accumulator, divides, and stores one full row.

#define DCOLS 256
#define D4    64   // DCOLS / 4

__global__ __launch_bounds__(256) void seg_mean_wave(
        const float* __restrict__ feats,
        const int* __restrict__ ids,
        int N, int S,
        float* __restrict__ out) {
    const int wave = threadIdx.x >> 6;          // 0..3
    const int lane = threadIdx.x & 63;
    const int s    = blockIdx.x * 4 + wave;
    if (s >= S) return;

    // All 64 lanes run the search; even lanes target s, odd lanes target s+1.
    // Two distinct addresses per iteration -> broadcast loads, no divergence.
    const int target = s + (lane & 1);
    int lo = 0, hi = N;
    while (lo < hi) {
        int mid = (lo + hi) >> 1;
        if (ids[mid] < target) lo = mid + 1;
        else hi = mid;
    }
    const int start = __shfl(lo, 0, 64);
    const int end   = __shfl(lo, 1, 64);
    const int count = end - start;

    const float4* f4 = reinterpret_cast<const float4*>(feats);

    float4 a0 = make_float4(0.f, 0.f, 0.f, 0.f);
    float4 a1 = make_float4(0.f, 0.f, 0.f, 0.f);
    float4 a2 = make_float4(0.f, 0.f, 0.f, 0.f);
    float4 a3 = make_float4(0.f, 0.f, 0.f, 0.f);

    int r = start;
    for (; r + 3 < end; r += 4) {
        float4 v0 = f4[(size_t)(r + 0) * D4 + lane];
        float4 v1 = f4[(size_t)(r + 1) * D4 + lane];
        float4 v2 = f4[(size_t)(r + 2) * D4 + lane];
        float4 v3 = f4[(size_t)(r + 3) * D4 + lane];
        a0.x += v0.x; a0.y += v0.y; a0.z += v0.z; a0.w += v0.w;
        a1.x += v1.x; a1.y += v1.y; a1.z += v1.z; a1.w += v1.w;
        a2.x += v2.x; a2.y += v2.y; a2.z += v2.z; a2.w += v2.w;
        a3.x += v3.x; a3.y += v3.y; a3.z += v3.z; a3.w += v3.w;
    }
    for (; r < end; ++r) {
        float4 v = f4[(size_t)r * D4 + lane];
        a0.x += v.x; a0.y += v.y; a0.z += v.z; a0.w += v.w;
    }

    const float cnt = (float)(count > 0 ? count : 1);
    float4 o;
    o.x = (a0.x + a1.x + a2.x + a3.x) / cnt;
    o.y = (a0.y + a1.y + a2.y + a3.y) / cnt;
    o.z = (a0.z + a1.z + a2.z + a3.z) / cnt;
    o.w = (a0.w + a1.w + a2.w + a3.w) / cnt;
    reinterpret_cast<float4*>(out)[(size_t)s * D4 + lane] = o;
}

extern "C" void kernel_launch(void* const* d_in, const int* in_sizes, int n_in,
                              void* d_out, int out_size, void* d_ws, size_t ws_size,
                              hipStream_t stream) {
    const float* feats = (const float*)d_in[0];
    const int*   ids   = (const int*)d_in[1];
    const int S = out_size / DCOLS;
    const int N = in_sizes[0] / DCOLS;

    const int blocks = (S + 3) / 4;
    seg_mean_wave<<<blocks, 256, 0, stream>>>(feats, ids, N, S, (float*)d_out);
}

// Round 4
// 174.123 us; speedup vs baseline: 1.1489x; 1.1489x over previous
//
#include <hip/hip_runtime.h>

// Segment-mean pooling: feats [N, 256] fp32, segment_ids [N] sorted int32,
// out [S, 256] fp32, S = out_size / 256.
//
// One wave per segment (64 lanes x float4 = 256 cols). 4 waves per block,
// no LDS, no barriers. Nontemporal loads/stores (pure stream, zero reuse)
// + 8-deep unrolled accumulation (8 outstanding 1KB loads per wave).

#define DCOLS 256
#define D4    64   // DCOLS / 4

typedef float f32x4 __attribute__((ext_vector_type(4)));

__global__ __launch_bounds__(256) void seg_mean_wave_nt(
        const float* __restrict__ feats,
        const int* __restrict__ ids,
        int N, int S,
        float* __restrict__ out) {
    const int wave = threadIdx.x >> 6;
    const int lane = threadIdx.x & 63;
    const int s    = blockIdx.x * 4 + wave;
    if (s >= S) return;

    // All lanes binary-search; even lanes target s, odd lanes s+1.
    const int target = s + (lane & 1);
    int lo = 0, hi = N;
    while (lo < hi) {
        int mid = (lo + hi) >> 1;
        if (ids[mid] < target) lo = mid + 1;
        else hi = mid;
    }
    const int start = __shfl(lo, 0, 64);
    const int end   = __shfl(lo, 1, 64);
    const int count = end - start;

    const f32x4* f4 = reinterpret_cast<const f32x4*>(feats);

    f32x4 a0 = 0.f, a1 = 0.f, a2 = 0.f, a3 = 0.f;
    f32x4 a4 = 0.f, a5 = 0.f, a6 = 0.f, a7 = 0.f;

    int r = start;
    for (; r + 7 < end; r += 8) {
        a0 += __builtin_nontemporal_load(&f4[(size_t)(r + 0) * D4 + lane]);
        a1 += __builtin_nontemporal_load(&f4[(size_t)(r + 1) * D4 + lane]);
        a2 += __builtin_nontemporal_load(&f4[(size_t)(r + 2) * D4 + lane]);
        a3 += __builtin_nontemporal_load(&f4[(size_t)(r + 3) * D4 + lane]);
        a4 += __builtin_nontemporal_load(&f4[(size_t)(r + 4) * D4 + lane]);
        a5 += __builtin_nontemporal_load(&f4[(size_t)(r + 5) * D4 + lane]);
        a6 += __builtin_nontemporal_load(&f4[(size_t)(r + 6) * D4 + lane]);
        a7 += __builtin_nontemporal_load(&f4[(size_t)(r + 7) * D4 + lane]);
    }
    for (; r + 3 < end; r += 4) {
        a0 += __builtin_nontemporal_load(&f4[(size_t)(r + 0) * D4 + lane]);
        a1 += __builtin_nontemporal_load(&f4[(size_t)(r + 1) * D4 + lane]);
        a2 += __builtin_nontemporal_load(&f4[(size_t)(r + 2) * D4 + lane]);
        a3 += __builtin_nontemporal_load(&f4[(size_t)(r + 3) * D4 + lane]);
    }
    for (; r < end; ++r) {
        a0 += __builtin_nontemporal_load(&f4[(size_t)r * D4 + lane]);
    }

    const float cnt = (float)(count > 0 ? count : 1);
    f32x4 sum = ((a0 + a1) + (a2 + a3)) + ((a4 + a5) + (a6 + a7));
    f32x4 o = sum / cnt;
    __builtin_nontemporal_store(o, reinterpret_cast<f32x4*>(out) + (size_t)s * D4 + lane);
}

extern "C" void kernel_launch(void* const* d_in, const int* in_sizes, int n_in,
                              void* d_out, int out_size, void* d_ws, size_t ws_size,
                              hipStream_t stream) {
    const float* feats = (const float*)d_in[0];
    const int*   ids   = (const int*)d_in[1];
    const int S = out_size / DCOLS;
    const int N = in_sizes[0] / DCOLS;

    const int blocks = (S + 3) / 4;
    seg_mean_wave_nt<<<blocks, 256, 0, stream>>>(feats, ids, N, S, (float*)d_out);
}